// Round 3
// baseline (207.923 us; speedup 1.0000x reference)
//
#include <hip/hip_runtime.h>

// ---------------------------------------------------------------------------
// 2-layer GCN, symmetric norm + self loops.
// Key structural trick: feat is [n,1], so every layer-1 output row is a
// function of TWO scalars:  y[u,c] = relu(W1[c]*px_u + b1[c]*py_u)
// with px_u = dinv_u^2 * A_u (A_u = raw scalar aggregate incl self loop),
// py_u = dinv_u.   (uses dinv*relu(x) == relu(dinv*x), dinv>0)
// Layer 2 therefore gathers an 8-byte float2 per edge (800KB table, fully
// L2-resident) instead of a 128B y-row over 12.8MB (which was 160MB of HBM
// fetch last round), and reconstructs y on the fly (2 fma + relu per lane).
// CSR built per call via bucketed counting sort (bucket = dst>>6) to keep
// scatter writes clustered.
// ---------------------------------------------------------------------------

#define TPB 256
#define NBMAX 4096   // max buckets in LDS histograms

// Detect int64 (low/high pairs) vs int32 edge layout: node ids < 2^31 so the
// int64 high words are exactly 0. Sample odd 32-bit positions.
__global__ void k_detect(const int* __restrict__ e32, int E, int* __restrict__ flag) {
    __shared__ int ok;
    if (threadIdx.x == 0) ok = 1;
    __syncthreads();
    int stride = E / 2048; if (stride < 1) stride = 1;
    bool bad = false;
#pragma unroll
    for (int i = 0; i < 8; ++i) {
        long k = (long)(threadIdx.x * 8 + i) * stride + 1;
        if (k < E && e32[2 * k + 1] != 0) bad = true;
    }
    if (bad) atomicAnd(&ok, 0);
    __syncthreads();
    if (threadIdx.x == 0) *flag = ok;   // 1 => int64, 0 => int32
}

__global__ void k_zero(int* __restrict__ p, int n) {
    int i = blockIdx.x * TPB + threadIdx.x;
    if (i < n) p[i] = 0;
}

// global bucket histogram (LDS-staged, few global atomics)
__global__ void k_hist(const int* __restrict__ e32, const int* __restrict__ flag,
                       int E, int NB, int shb, int* __restrict__ gHist) {
    __shared__ int sh[NBMAX];
    for (int i = threadIdx.x; i < NB; i += TPB) sh[i] = 0;
    __syncthreads();
    int f = *flag;
    int stride = gridDim.x * TPB;
    for (int e = blockIdx.x * TPB + threadIdx.x; e < E; e += stride) {
        int d = f ? ((const int2*)e32)[E + e].x : e32[E + e];
        atomicAdd(&sh[d >> shb], 1);
    }
    __syncthreads();
    for (int i = threadIdx.x; i < NB; i += TPB)
        if (sh[i]) atomicAdd(&gHist[i], sh[i]);
}

// one-block exclusive scan of NB bucket counts -> base, cursor; rowptr[n]=E
__global__ void k_scan(const int* __restrict__ gHist, int NB, int E,
                       int* __restrict__ base, int* __restrict__ cursor,
                       int* __restrict__ rowptr, int n) {
    __shared__ int s[TPB];
    int K = (NB + TPB - 1) / TPB;
    int t = threadIdx.x;
    int i0 = t * K;
    int tot = 0;
    for (int k = 0; k < K; ++k) { int i = i0 + k; if (i < NB) tot += gHist[i]; }
    s[t] = tot;
    __syncthreads();
    for (int off = 1; off < TPB; off <<= 1) {
        int v = s[t];
        int u = (t >= off) ? s[t - off] : 0;
        __syncthreads();
        s[t] = v + u;
        __syncthreads();
    }
    int run = s[t] - tot;   // exclusive
    for (int k = 0; k < K; ++k) {
        int i = i0 + k;
        if (i < NB) { int h = gHist[i]; base[i] = run; cursor[i] = run; run += h; }
    }
    if (t == 0) { base[NB] = E; rowptr[n] = E; }
}

// stage edges bucket-major: per-chunk LDS hist -> one reservation atomic per
// (bucket,block) -> scatter packed (src | (dst&((1<<shb)-1)) << (32-shb)).
__global__ void k_stage(const int* __restrict__ e32, const int* __restrict__ flag,
                        int E, int NB, int shb, int* __restrict__ cursor,
                        unsigned int* __restrict__ P, int chunk) {
    __shared__ int sh[NBMAX];
    int c0 = blockIdx.x * chunk;
    int c1 = c0 + chunk; if (c1 > E) c1 = E;
    for (int i = threadIdx.x; i < NB; i += TPB) sh[i] = 0;
    __syncthreads();
    int f = *flag;
    for (int e = c0 + threadIdx.x; e < c1; e += TPB) {
        int d = f ? ((const int2*)e32)[E + e].x : e32[E + e];
        atomicAdd(&sh[d >> shb], 1);
    }
    __syncthreads();
    for (int i = threadIdx.x; i < NB; i += TPB) {
        int c = sh[i];
        sh[i] = c ? atomicAdd(&cursor[i], c) : 0;   // LDS cell now holds cursor
    }
    __syncthreads();
    int lshift = 32 - shb;
    for (int e = c0 + threadIdx.x; e < c1; e += TPB) {
        int s, d;
        if (f) { s = ((const int2*)e32)[e].x; d = ((const int2*)e32)[E + e].x; }
        else   { s = e32[e];                  d = e32[E + e]; }
        int b = d >> shb;
        int pos = atomicAdd(&sh[b], 1);
        P[pos] = (unsigned)s | ((unsigned)(d & ((1 << shb) - 1)) << lshift);
    }
}

// one block per bucket: node-major sort within bucket (writes confined to an
// ~8KB window), plus rowptr / dinv / g for the bucket's nodes.
__global__ void k_build(const unsigned int* __restrict__ P, const int* __restrict__ base,
                        int shb, int n, const float* __restrict__ feat,
                        int* __restrict__ csr, int* __restrict__ rowptr,
                        float* __restrict__ dinv, float* __restrict__ g) {
    __shared__ int cnt[TPB];
    __shared__ int loc[TPB];
    int b = blockIdx.x;
    int nb = 1 << shb;              // nodes per bucket (<= TPB)
    int v0 = b << shb;
    int t = threadIdx.x;
    cnt[t] = 0;
    __syncthreads();
    int p0 = base[b], p1 = base[b + 1];
    int lshift = 32 - shb;
    unsigned mask = (1u << lshift) - 1;
    for (int p = p0 + t; p < p1; p += TPB) {
        unsigned e = P[p];
        atomicAdd(&cnt[e >> lshift], 1);
    }
    __syncthreads();
    int c = cnt[t];
    loc[t] = c;
    __syncthreads();
    for (int off = 1; off < TPB; off <<= 1) {
        int v = loc[t];
        int u = (t >= off) ? loc[t - off] : 0;
        __syncthreads();
        loc[t] = v + u;
        __syncthreads();
    }
    int excl = loc[t] - c;
    int v = v0 + t;
    if (t < nb && v < n) {
        rowptr[v] = p0 + excl;
        float di = rsqrtf((float)(c + 1));
        dinv[v] = di;
        g[v] = di * feat[v];
    }
    cnt[t] = p0 + excl;             // reuse as global cursor
    __syncthreads();
    for (int p = p0 + t; p < p1; p += TPB) {
        unsigned e = P[p];
        int node = e >> lshift;
        int pos = atomicAdd(&cnt[node], 1);
        csr[pos] = (int)(e & mask);
    }
}

// layer 1: scalar gather; writes p[v] = (dinv^2 * A_v, dinv)  (8B per node)
__global__ void k_l1(const float* __restrict__ g, const float* __restrict__ dinv,
                     const int* __restrict__ rowptr, const int* __restrict__ csr,
                     int n, float2* __restrict__ p) {
    int v = blockIdx.x * TPB + threadIdx.x;
    if (v >= n) return;
    float sum = g[v];                       // self loop
    int r0 = rowptr[v], r1 = rowptr[v + 1];
    int i = r0;
    for (; i + 3 < r1; i += 4) {
        int u0 = csr[i], u1 = csr[i + 1], u2 = csr[i + 2], u3 = csr[i + 3];
        sum += g[u0] + g[u1] + g[u2] + g[u3];
    }
    for (; i < r1; ++i) sum += g[csr[i]];
    float dv = dinv[v];
    p[v] = make_float2(dv * dv * sum, dv);
}

// layer 2: 8 nodes/block, 32 lanes = 32 channels per node. Per edge gather an
// 8B float2 (L2-resident) and reconstruct y[u,c] = relu(W1c*px + b1c*py).
// Then 32x64 matmul from LDS.
__global__ void k_l2(const float2* __restrict__ p, const int* __restrict__ rowptr,
                     const int* __restrict__ csr,
                     const float* __restrict__ W1, const float* __restrict__ b1,
                     const float* __restrict__ W2, const float* __restrict__ b2,
                     float* __restrict__ out, int n) {
    __shared__ float sW[32 * 64];
    __shared__ float sb[64];
    __shared__ float sagg[8][33];
    int t = threadIdx.x;
    for (int i = t; i < 32 * 64; i += TPB) sW[i] = W2[i];
    if (t < 64) sb[t] = b2[t];

    int vl = t >> 5;          // node slot (0..7)
    int c  = t & 31;          // channel (0..31)
    int v  = blockIdx.x * 8 + vl;

    float acc = 0.f;
    float py_v = 0.f;
    if (v < n) {
        float w1c = W1[c], b1c = b1[c];
        float2 pv = p[v];
        py_v = pv.y;
        acc = fmaxf(fmaf(w1c, pv.x, b1c * pv.y), 0.f);   // self loop
        int r0 = rowptr[v], r1 = rowptr[v + 1];
        int i = r0;
        for (; i + 3 < r1; i += 4) {
            int u0 = csr[i], u1 = csr[i + 1], u2 = csr[i + 2], u3 = csr[i + 3];
            float2 q0 = p[u0], q1 = p[u1], q2 = p[u2], q3 = p[u3];
            acc += fmaxf(fmaf(w1c, q0.x, b1c * q0.y), 0.f);
            acc += fmaxf(fmaf(w1c, q1.x, b1c * q1.y), 0.f);
            acc += fmaxf(fmaf(w1c, q2.x, b1c * q2.y), 0.f);
            acc += fmaxf(fmaf(w1c, q3.x, b1c * q3.y), 0.f);
        }
        for (; i < r1; ++i) {
            float2 q = p[csr[i]];
            acc += fmaxf(fmaf(w1c, q.x, b1c * q.y), 0.f);
        }
        acc *= py_v;                                      // dinv[v]
    }
    sagg[vl][c] = acc;
    __syncthreads();

    if (v < n) {
        float o0 = sb[c], o1 = sb[c + 32];
#pragma unroll
        for (int j = 0; j < 32; ++j) {
            float a = sagg[vl][j];
            o0 += a * sW[j * 64 + c];
            o1 += a * sW[j * 64 + 32 + c];
        }
        out[v * 64 + c]      = fmaxf(o0, 0.f);
        out[v * 64 + 32 + c] = fmaxf(o1, 0.f);
    }
}

static inline size_t align256(size_t x) { return (x + 255) & ~(size_t)255; }

extern "C" void kernel_launch(void* const* d_in, const int* in_sizes, int n_in,
                              void* d_out, int out_size, void* d_ws, size_t ws_size,
                              hipStream_t stream) {
    const float* feat = (const float*)d_in[0];
    const int*   e32  = (const int*)d_in[1];
    const float* W1   = (const float*)d_in[2];
    const float* b1   = (const float*)d_in[3];
    const float* W2   = (const float*)d_in[4];
    const float* b2   = (const float*)d_in[5];
    float* out = (float*)d_out;

    int n = in_sizes[0];         // 100000
    int E = in_sizes[1] / 2;     // 3200000

    int shb = 6;                                     // 64 nodes / bucket
    while ((((n + (1 << shb) - 1) >> shb) > NBMAX) && shb < 12) shb++;
    int NB = (n + (1 << shb) - 1) >> shb;            // 1563

    char* w = (char*)d_ws;
    size_t off = 0;
    auto alloc = [&](size_t bytes) -> char* { char* p = w + off; off = align256(off + bytes); return p; };
    unsigned int* P = (unsigned int*)alloc((size_t)E * 4);   // bucket staging
    int*   csr    = (int*)alloc((size_t)E * 4);
    int*   gHist  = (int*)alloc((size_t)NB * 4);
    int*   base   = (int*)alloc((size_t)(NB + 1) * 4);
    int*   cursor = (int*)alloc((size_t)NB * 4);
    int*   rowptr = (int*)alloc((size_t)(n + 1) * 4);
    float* dinv   = (float*)alloc((size_t)n * 4);
    float* g      = (float*)alloc((size_t)n * 4);
    float2* p2    = (float2*)alloc((size_t)n * 8);
    int*   flag   = (int*)alloc(4);

    int chunk = (E + 255) / 256;                      // 256 staging blocks
    int gC = (E + chunk - 1) / chunk;
    int gN = (n + TPB - 1) / TPB;

    hipLaunchKernelGGL(k_detect, dim3(1),   dim3(TPB), 0, stream, e32, E, flag);
    hipLaunchKernelGGL(k_zero,   dim3((NB + TPB - 1) / TPB), dim3(TPB), 0, stream, gHist, NB);
    hipLaunchKernelGGL(k_hist,   dim3(256), dim3(TPB), 0, stream, e32, flag, E, NB, shb, gHist);
    hipLaunchKernelGGL(k_scan,   dim3(1),   dim3(TPB), 0, stream, gHist, NB, E, base, cursor, rowptr, n);
    hipLaunchKernelGGL(k_stage,  dim3(gC),  dim3(TPB), 0, stream, e32, flag, E, NB, shb, cursor, P, chunk);
    hipLaunchKernelGGL(k_build,  dim3(NB),  dim3(TPB), 0, stream, P, base, shb, n, feat, csr, rowptr, dinv, g);
    hipLaunchKernelGGL(k_l1,     dim3(gN),  dim3(TPB), 0, stream, g, dinv, rowptr, csr, n, p2);
    hipLaunchKernelGGL(k_l2,     dim3((n + 7) / 8), dim3(TPB), 0, stream, p2, rowptr, csr, W1, b1, W2, b2, out, n);
}